// Round 1
// baseline (293.676 us; speedup 1.0000x reference)
//
#include <hip/hip_runtime.h>
#include <math.h>

#define BB   4
#define HH   16
#define NN   4096
#define DD   64
#define MM   256
#define TOPN 16
#define ROWS 32
#define NTILES (NN / ROWS)   // 128

// ---------------------------------------------------------------------------
// Kernel 1: per (b, 32-row n-tile), loop over all 16 heads.
//   scores = (q * 2^-3) . ck^T   (pow2 scale applied to q, exact)
//   softmax over M=256 (stable), write probs, accumulate importance in regs.
// Thread layout: 8 row-groups (rg) x 32 lanes (c). Microtile: 4 rows x 4 m.
//   m = hh*128 + mm*64 + 2c + j   (hh = ck half, mm = 0/1, j = 0/1)
// ---------------------------------------------------------------------------
__global__ __launch_bounds__(256)
void k_scores(const float* __restrict__ q, const float* __restrict__ ck,
              float* __restrict__ out_scores, float* __restrict__ imp_out) {
  __shared__ float ckT[DD][MM / 2];  // [d][m'] 64x128 = 32 KB (half of M)
  __shared__ float qT[DD][ROWS];     // [d][row] 64x32 = 8 KB

  const int bx  = blockIdx.x;
  const int b   = bx / NTILES;
  const int n0  = (bx % NTILES) * ROWS;
  const int tid = threadIdx.x;
  const int rg  = tid >> 5;  // 0..7
  const int c   = tid & 31;  // 0..31

  float imp[4][8];
#pragma unroll
  for (int i = 0; i < 4; i++)
#pragma unroll
    for (int k = 0; k < 8; k++) imp[i][k] = 0.0f;

  for (int h = 0; h < HH; ++h) {
    float acc[4][8];
#pragma unroll
    for (int i = 0; i < 4; i++)
#pragma unroll
      for (int k = 0; k < 8; k++) acc[i][k] = 0.0f;

#pragma unroll
    for (int hh = 0; hh < 2; ++hh) {
      __syncthreads();  // protect LDS from previous compute phase

      if (hh == 0) {
        // stage qT: row = tid&31, 8 d's per thread (dch = tid>>5)
        const int row = tid & 31;
        const int dch = tid >> 5;
        const float* qp =
            q + (((size_t)(b * HH + h) * NN) + n0 + row) * DD + dch * 8;
        const float4 a0 = *(const float4*)(qp);
        const float4 a1 = *(const float4*)(qp + 4);
        const float s = 0.125f;  // D^-1/2, exact power of two
        qT[dch * 8 + 0][row] = a0.x * s;
        qT[dch * 8 + 1][row] = a0.y * s;
        qT[dch * 8 + 2][row] = a0.z * s;
        qT[dch * 8 + 3][row] = a0.w * s;
        qT[dch * 8 + 4][row] = a1.x * s;
        qT[dch * 8 + 5][row] = a1.y * s;
        qT[dch * 8 + 6][row] = a1.z * s;
        qT[dch * 8 + 7][row] = a1.w * s;
      }
      {
        // stage ckT half hh: m rows [hh*128, hh*128+128), transposed
        const int mrow = tid & 127;
        const int dh   = tid >> 7;  // 0/1 -> d 0..31 / 32..63
        const float* cp =
            ck + (((size_t)(b * HH + h) * MM) + hh * 128 + mrow) * DD + dh * 32;
#pragma unroll
        for (int k = 0; k < 8; k++) {
          const float4 a = *(const float4*)(cp + k * 4);
          ckT[dh * 32 + k * 4 + 0][mrow] = a.x;
          ckT[dh * 32 + k * 4 + 1][mrow] = a.y;
          ckT[dh * 32 + k * 4 + 2][mrow] = a.z;
          ckT[dh * 32 + k * 4 + 3][mrow] = a.w;
        }
      }
      __syncthreads();

#pragma unroll 8
      for (int d = 0; d < DD; ++d) {
        const float4 qv = *(const float4*)&qT[d][rg * 4];
        const float2 c0 = *(const float2*)&ckT[d][2 * c];
        const float2 c1 = *(const float2*)&ckT[d][64 + 2 * c];
        const float qa0 = qv.x, qa1 = qv.y, qa2 = qv.z, qa3 = qv.w;
        acc[0][hh * 4 + 0] = fmaf(qa0, c0.x, acc[0][hh * 4 + 0]);
        acc[0][hh * 4 + 1] = fmaf(qa0, c0.y, acc[0][hh * 4 + 1]);
        acc[0][hh * 4 + 2] = fmaf(qa0, c1.x, acc[0][hh * 4 + 2]);
        acc[0][hh * 4 + 3] = fmaf(qa0, c1.y, acc[0][hh * 4 + 3]);
        acc[1][hh * 4 + 0] = fmaf(qa1, c0.x, acc[1][hh * 4 + 0]);
        acc[1][hh * 4 + 1] = fmaf(qa1, c0.y, acc[1][hh * 4 + 1]);
        acc[1][hh * 4 + 2] = fmaf(qa1, c1.x, acc[1][hh * 4 + 2]);
        acc[1][hh * 4 + 3] = fmaf(qa1, c1.y, acc[1][hh * 4 + 3]);
        acc[2][hh * 4 + 0] = fmaf(qa2, c0.x, acc[2][hh * 4 + 0]);
        acc[2][hh * 4 + 1] = fmaf(qa2, c0.y, acc[2][hh * 4 + 1]);
        acc[2][hh * 4 + 2] = fmaf(qa2, c1.x, acc[2][hh * 4 + 2]);
        acc[2][hh * 4 + 3] = fmaf(qa2, c1.y, acc[2][hh * 4 + 3]);
        acc[3][hh * 4 + 0] = fmaf(qa3, c0.x, acc[3][hh * 4 + 0]);
        acc[3][hh * 4 + 1] = fmaf(qa3, c0.y, acc[3][hh * 4 + 1]);
        acc[3][hh * 4 + 2] = fmaf(qa3, c1.x, acc[3][hh * 4 + 2]);
        acc[3][hh * 4 + 3] = fmaf(qa3, c1.y, acc[3][hh * 4 + 3]);
      }
    }

    // ---- softmax over the 256 m's of each of this thread's 4 rows ----
#pragma unroll
    for (int i = 0; i < 4; i++) {
      float mx = acc[i][0];
#pragma unroll
      for (int k = 1; k < 8; k++) mx = fmaxf(mx, acc[i][k]);
#pragma unroll
      for (int off = 1; off < 32; off <<= 1)
        mx = fmaxf(mx, __shfl_xor(mx, off, 64));

      float sum = 0.0f;
#pragma unroll
      for (int k = 0; k < 8; k++) {
        acc[i][k] = expf(acc[i][k] - mx);  // acc now holds unnormalized p
        sum += acc[i][k];
      }
#pragma unroll
      for (int off = 1; off < 32; off <<= 1) sum += __shfl_xor(sum, off, 64);

#pragma unroll
      for (int k = 0; k < 8; k++) acc[i][k] = acc[i][k] / sum;  // exact div

      float* op =
          out_scores + (((size_t)(b * HH + h) * NN) + n0 + rg * 4 + i) * MM;
      *(float2*)(op + 2 * c)       = make_float2(acc[i][0], acc[i][1]);
      *(float2*)(op + 64 + 2 * c)  = make_float2(acc[i][2], acc[i][3]);
      *(float2*)(op + 128 + 2 * c) = make_float2(acc[i][4], acc[i][5]);
      *(float2*)(op + 192 + 2 * c) = make_float2(acc[i][6], acc[i][7]);

#pragma unroll
      for (int k = 0; k < 8; k++) imp[i][k] += acc[i][k];
    }
  }

  if (imp_out != nullptr) {
#pragma unroll
    for (int i = 0; i < 4; i++) {
      float* op = imp_out + ((size_t)b * NN + n0 + rg * 4 + i) * MM;
      *(float2*)(op + 2 * c)       = make_float2(imp[i][0], imp[i][1]);
      *(float2*)(op + 64 + 2 * c)  = make_float2(imp[i][2], imp[i][3]);
      *(float2*)(op + 128 + 2 * c) = make_float2(imp[i][4], imp[i][5]);
      *(float2*)(op + 192 + 2 * c) = make_float2(imp[i][6], imp[i][7]);
    }
  }
}

// ---------------------------------------------------------------------------
// Top-k selection: one 64-lane wave per (b,n) row. 16 iterations of
// argmax with lower-index tiebreak == jax.lax.top_k stable semantics.
// ---------------------------------------------------------------------------
__device__ __forceinline__ void topk_row(float vals[4], int lane, int b, int n,
                                         float* __restrict__ out_idx) {
  int keep = 0;
#pragma unroll
  for (int it = 0; it < TOPN; ++it) {
    float bv = vals[0];
    int bi = lane * 4;
#pragma unroll
    for (int j = 1; j < 4; j++) {
      if (vals[j] > bv) { bv = vals[j]; bi = lane * 4 + j; }
    }
    for (int off = 1; off < 64; off <<= 1) {
      const float ov = __shfl_xor(bv, off, 64);
      const int oi = __shfl_xor(bi, off, 64);
      if (ov > bv || (ov == bv && oi < bi)) { bv = ov; bi = oi; }
    }
    if (lane == it) keep = bi;
    if ((bi >> 2) == lane) vals[bi & 3] = -INFINITY;
  }
  if (lane < TOPN)
    out_idx[((size_t)b * NN + n) * TOPN + lane] = (float)keep;
}

__global__ __launch_bounds__(256)
void k_topk(const float* __restrict__ imp, float* __restrict__ out_idx) {
  const int wave = blockIdx.x * 4 + (threadIdx.x >> 6);
  const int lane = threadIdx.x & 63;
  const int b = wave >> 12;        // wave / NN
  const int n = wave & (NN - 1);
  const float4 v = *(const float4*)(imp + ((size_t)b * NN + n) * MM + lane * 4);
  float vals[4] = {v.x, v.y, v.z, v.w};
  topk_row(vals, lane, b, n, out_idx);
}

__global__ __launch_bounds__(256)
void k_topk_from_scores(const float* __restrict__ scores,
                        float* __restrict__ out_idx) {
  const int wave = blockIdx.x * 4 + (threadIdx.x >> 6);
  const int lane = threadIdx.x & 63;
  const int b = wave >> 12;
  const int n = wave & (NN - 1);
  float vals[4] = {0.f, 0.f, 0.f, 0.f};
  for (int h = 0; h < HH; ++h) {
    const float4 s = *(const float4*)(scores +
                                      (((size_t)(b * HH + h) * NN) + n) * MM +
                                      lane * 4);
    vals[0] += s.x; vals[1] += s.y; vals[2] += s.z; vals[3] += s.w;
  }
  topk_row(vals, lane, b, n, out_idx);
}

extern "C" void kernel_launch(void* const* d_in, const int* in_sizes, int n_in,
                              void* d_out, int out_size, void* d_ws,
                              size_t ws_size, hipStream_t stream) {
  const float* q  = (const float*)d_in[0];
  const float* ck = (const float*)d_in[1];
  // d_in[2] (k) and d_in[3] (v) are unused by the reference output.

  float* out        = (float*)d_out;
  float* out_idx    = out;                              // B*N*16 floats
  float* out_scores = out + (size_t)BB * NN * TOPN;     // B*H*N*M floats

  const size_t imp_bytes = (size_t)BB * NN * MM * sizeof(float);
  float* imp = (ws_size >= imp_bytes) ? (float*)d_ws : nullptr;

  k_scores<<<BB * NTILES, 256, 0, stream>>>(q, ck, out_scores, imp);

  if (imp != nullptr) {
    k_topk<<<(BB * NN) / 4, 256, 0, stream>>>(imp, out_idx);
  } else {
    k_topk_from_scores<<<(BB * NN) / 4, 256, 0, stream>>>(out_scores, out_idx);
  }
}

// Round 2
// 211.831 us; speedup vs baseline: 1.3864x; 1.3864x over previous
//
#include <hip/hip_runtime.h>
#include <math.h>

#define BB   4
#define HH   16
#define NN   4096
#define DD   64
#define MM   256
#define TOPN 16
#define ROWS 32
#define NTILES (NN / ROWS)   // 128

// ---------------------------------------------------------------------------
// Kernel 1: per (b, 32-row n-tile, head-group), loop over HPB heads.
//   scores = (q * 2^-3) . ck^T   (pow2 scale applied to q, exact)
//   softmax over M=256 (stable), write probs, accumulate importance in regs,
//   dump per-head-group partial importance to ws.
// Thread layout: 8 row-groups (rg) x 32 lanes (c). Microtile: 4 rows x 8 m.
//   m = hh*128 + mm*64 + 2c + j   (hh = ck half, mm = 0/1, j = 0/1)
// ---------------------------------------------------------------------------
__global__ __launch_bounds__(256)
void k_scores(const float* __restrict__ q, const float* __restrict__ ck,
              float* __restrict__ out_scores, float* __restrict__ imp_out,
              int hpb) {
  __shared__ float ckT[DD][MM / 2];  // [d][m'] 64x128 = 32 KB (half of M)
  __shared__ float qT[DD][ROWS];     // [d][row] 64x32 = 8 KB

  const int bx  = blockIdx.x;
  const int hg  = blockIdx.y;        // head-group
  const int b   = bx / NTILES;
  const int n0  = (bx % NTILES) * ROWS;
  const int tid = threadIdx.x;
  const int rg  = tid >> 5;  // 0..7
  const int c   = tid & 31;  // 0..31

  float imp[4][8];
#pragma unroll
  for (int i = 0; i < 4; i++)
#pragma unroll
    for (int k = 0; k < 8; k++) imp[i][k] = 0.0f;

  const int h_end = (hg + 1) * hpb;
  for (int h = hg * hpb; h < h_end; ++h) {
    float acc[4][8];
#pragma unroll
    for (int i = 0; i < 4; i++)
#pragma unroll
      for (int k = 0; k < 8; k++) acc[i][k] = 0.0f;

#pragma unroll
    for (int hh = 0; hh < 2; ++hh) {
      __syncthreads();  // protect LDS from previous compute phase

      if (hh == 0) {
        // stage qT: row = tid&31, 8 d's per thread (dch = tid>>5)
        const int row = tid & 31;
        const int dch = tid >> 5;
        const float* qp =
            q + (((size_t)(b * HH + h) * NN) + n0 + row) * DD + dch * 8;
        const float4 a0 = *(const float4*)(qp);
        const float4 a1 = *(const float4*)(qp + 4);
        const float s = 0.125f;  // D^-1/2, exact power of two
        qT[dch * 8 + 0][row] = a0.x * s;
        qT[dch * 8 + 1][row] = a0.y * s;
        qT[dch * 8 + 2][row] = a0.z * s;
        qT[dch * 8 + 3][row] = a0.w * s;
        qT[dch * 8 + 4][row] = a1.x * s;
        qT[dch * 8 + 5][row] = a1.y * s;
        qT[dch * 8 + 6][row] = a1.z * s;
        qT[dch * 8 + 7][row] = a1.w * s;
      }
      {
        // stage ckT half hh: m rows [hh*128, hh*128+128), transposed
        const int mrow = tid & 127;
        const int dh   = tid >> 7;  // 0/1 -> d 0..31 / 32..63
        const float* cp =
            ck + (((size_t)(b * HH + h) * MM) + hh * 128 + mrow) * DD + dh * 32;
#pragma unroll
        for (int k = 0; k < 8; k++) {
          const float4 a = *(const float4*)(cp + k * 4);
          ckT[dh * 32 + k * 4 + 0][mrow] = a.x;
          ckT[dh * 32 + k * 4 + 1][mrow] = a.y;
          ckT[dh * 32 + k * 4 + 2][mrow] = a.z;
          ckT[dh * 32 + k * 4 + 3][mrow] = a.w;
        }
      }
      __syncthreads();

#pragma unroll 8
      for (int d = 0; d < DD; ++d) {
        const float4 qv = *(const float4*)&qT[d][rg * 4];
        const float2 c0 = *(const float2*)&ckT[d][2 * c];
        const float2 c1 = *(const float2*)&ckT[d][64 + 2 * c];
        const float qa0 = qv.x, qa1 = qv.y, qa2 = qv.z, qa3 = qv.w;
        acc[0][hh * 4 + 0] = fmaf(qa0, c0.x, acc[0][hh * 4 + 0]);
        acc[0][hh * 4 + 1] = fmaf(qa0, c0.y, acc[0][hh * 4 + 1]);
        acc[0][hh * 4 + 2] = fmaf(qa0, c1.x, acc[0][hh * 4 + 2]);
        acc[0][hh * 4 + 3] = fmaf(qa0, c1.y, acc[0][hh * 4 + 3]);
        acc[1][hh * 4 + 0] = fmaf(qa1, c0.x, acc[1][hh * 4 + 0]);
        acc[1][hh * 4 + 1] = fmaf(qa1, c0.y, acc[1][hh * 4 + 1]);
        acc[1][hh * 4 + 2] = fmaf(qa1, c1.x, acc[1][hh * 4 + 2]);
        acc[1][hh * 4 + 3] = fmaf(qa1, c1.y, acc[1][hh * 4 + 3]);
        acc[2][hh * 4 + 0] = fmaf(qa2, c0.x, acc[2][hh * 4 + 0]);
        acc[2][hh * 4 + 1] = fmaf(qa2, c0.y, acc[2][hh * 4 + 1]);
        acc[2][hh * 4 + 2] = fmaf(qa2, c1.x, acc[2][hh * 4 + 2]);
        acc[2][hh * 4 + 3] = fmaf(qa2, c1.y, acc[2][hh * 4 + 3]);
        acc[3][hh * 4 + 0] = fmaf(qa3, c0.x, acc[3][hh * 4 + 0]);
        acc[3][hh * 4 + 1] = fmaf(qa3, c0.y, acc[3][hh * 4 + 1]);
        acc[3][hh * 4 + 2] = fmaf(qa3, c1.x, acc[3][hh * 4 + 2]);
        acc[3][hh * 4 + 3] = fmaf(qa3, c1.y, acc[3][hh * 4 + 3]);
      }
    }

    // ---- softmax over the 256 m's of each of this thread's 4 rows ----
#pragma unroll
    for (int i = 0; i < 4; i++) {
      float mx = acc[i][0];
#pragma unroll
      for (int k = 1; k < 8; k++) mx = fmaxf(mx, acc[i][k]);
#pragma unroll
      for (int off = 1; off < 32; off <<= 1)
        mx = fmaxf(mx, __shfl_xor(mx, off, 64));

      float sum = 0.0f;
#pragma unroll
      for (int k = 0; k < 8; k++) {
        acc[i][k] = __expf(acc[i][k] - mx);  // v_exp_f32 path
        sum += acc[i][k];
      }
#pragma unroll
      for (int off = 1; off < 32; off <<= 1) sum += __shfl_xor(sum, off, 64);

      const float inv = 1.0f / sum;  // one accurate div per row
#pragma unroll
      for (int k = 0; k < 8; k++) acc[i][k] *= inv;

      float* op =
          out_scores + (((size_t)(b * HH + h) * NN) + n0 + rg * 4 + i) * MM;
      *(float2*)(op + 2 * c)       = make_float2(acc[i][0], acc[i][1]);
      *(float2*)(op + 64 + 2 * c)  = make_float2(acc[i][2], acc[i][3]);
      *(float2*)(op + 128 + 2 * c) = make_float2(acc[i][4], acc[i][5]);
      *(float2*)(op + 192 + 2 * c) = make_float2(acc[i][6], acc[i][7]);

#pragma unroll
      for (int k = 0; k < 8; k++) imp[i][k] += acc[i][k];
    }
  }

  if (imp_out != nullptr) {
    float* base = imp_out + (size_t)hg * BB * NN * MM;
#pragma unroll
    for (int i = 0; i < 4; i++) {
      float* op = base + ((size_t)b * NN + n0 + rg * 4 + i) * MM;
      *(float2*)(op + 2 * c)       = make_float2(imp[i][0], imp[i][1]);
      *(float2*)(op + 64 + 2 * c)  = make_float2(imp[i][2], imp[i][3]);
      *(float2*)(op + 128 + 2 * c) = make_float2(imp[i][4], imp[i][5]);
      *(float2*)(op + 192 + 2 * c) = make_float2(imp[i][6], imp[i][7]);
    }
  }
}

// ---------------------------------------------------------------------------
// Top-k selection: one 64-lane wave per (b,n) row. 16 iterations of
// argmax with lower-index tiebreak == jax.lax.top_k stable semantics.
// ---------------------------------------------------------------------------
__device__ __forceinline__ void topk_row(float vals[4], int lane, int b, int n,
                                         float* __restrict__ out_idx) {
  int keep = 0;
#pragma unroll
  for (int it = 0; it < TOPN; ++it) {
    float bv = vals[0];
    int bi = lane * 4;
#pragma unroll
    for (int j = 1; j < 4; j++) {
      if (vals[j] > bv) { bv = vals[j]; bi = lane * 4 + j; }
    }
    for (int off = 1; off < 64; off <<= 1) {
      const float ov = __shfl_xor(bv, off, 64);
      const int oi = __shfl_xor(bi, off, 64);
      if (ov > bv || (ov == bv && oi < bi)) { bv = ov; bi = oi; }
    }
    if (lane == it) keep = bi;
    if ((bi >> 2) == lane) vals[bi & 3] = -INFINITY;
  }
  if (lane < TOPN)
    out_idx[((size_t)b * NN + n) * TOPN + lane] = (float)keep;
}

__global__ __launch_bounds__(256)
void k_topk(const float* __restrict__ imp, float* __restrict__ out_idx,
            int nsplit) {
  const int wave = blockIdx.x * 4 + (threadIdx.x >> 6);
  const int lane = threadIdx.x & 63;
  const int b = wave >> 12;        // wave / NN
  const int n = wave & (NN - 1);
  float vals[4] = {0.f, 0.f, 0.f, 0.f};
  for (int s = 0; s < nsplit; ++s) {
    const float4 v = *(const float4*)(imp + (size_t)s * BB * NN * MM +
                                      ((size_t)b * NN + n) * MM + lane * 4);
    vals[0] += v.x; vals[1] += v.y; vals[2] += v.z; vals[3] += v.w;
  }
  topk_row(vals, lane, b, n, out_idx);
}

__global__ __launch_bounds__(256)
void k_topk_from_scores(const float* __restrict__ scores,
                        float* __restrict__ out_idx) {
  const int wave = blockIdx.x * 4 + (threadIdx.x >> 6);
  const int lane = threadIdx.x & 63;
  const int b = wave >> 12;
  const int n = wave & (NN - 1);
  float vals[4] = {0.f, 0.f, 0.f, 0.f};
  for (int h = 0; h < HH; ++h) {
    const float4 s = *(const float4*)(scores +
                                      (((size_t)(b * HH + h) * NN) + n) * MM +
                                      lane * 4);
    vals[0] += s.x; vals[1] += s.y; vals[2] += s.z; vals[3] += s.w;
  }
  topk_row(vals, lane, b, n, out_idx);
}

extern "C" void kernel_launch(void* const* d_in, const int* in_sizes, int n_in,
                              void* d_out, int out_size, void* d_ws,
                              size_t ws_size, hipStream_t stream) {
  const float* q  = (const float*)d_in[0];
  const float* ck = (const float*)d_in[1];
  // d_in[2] (k) and d_in[3] (v) are unused by the reference output.

  float* out        = (float*)d_out;
  float* out_idx    = out;                              // B*N*16 floats
  float* out_scores = out + (size_t)BB * NN * TOPN;     // B*H*N*M floats

  const size_t one = (size_t)BB * NN * MM * sizeof(float);  // 16.78 MB

  int hsplit;
  float* imp;
  if (ws_size >= 2 * one) { hsplit = 2; imp = (float*)d_ws; }
  else if (ws_size >= one) { hsplit = 1; imp = (float*)d_ws; }
  else { hsplit = 1; imp = nullptr; }

  dim3 grid(BB * NTILES, hsplit);
  k_scores<<<grid, 256, 0, stream>>>(q, ck, out_scores, imp, HH / hsplit);

  if (imp != nullptr) {
    k_topk<<<(BB * NN) / 4, 256, 0, stream>>>(imp, out_idx, hsplit);
  } else {
    k_topk_from_scores<<<(BB * NN) / 4, 256, 0, stream>>>(out_scores, out_idx);
  }
}